// Round 1
// baseline (244.638 us; speedup 1.0000x reference)
//
#include <hip/hip_runtime.h>

// Problem constants (must match reference)
#define Bn 16
#define An 3
#define Cn 80
#define Hn 76
#define Wn 76
#define Tn 50
#define HWn (Hn*Wn)                 // 5776
#define NCELL (Bn*An*Hn*Wn)         // 277248
#define NTHREADS 256
#define NBLK (NCELL/NTHREADS)       // 1083 (exact)

static_assert(NCELL % NTHREADS == 0, "grid must be exact");
static_assert(NCELL % 4 == 0, "word init requires /4");

__device__ __forceinline__ float sigmoidf_(float z){ return 1.0f/(1.0f+expf(-z)); }

// bce(p,t) = -( t*max(log p, -100) + (1-t)*max(log(1-p), -100) )
// clip BEFORE multiply: 0 * (-100) = 0, never 0 * -inf.
__device__ __forceinline__ float bcef_(float p, float t){
  float lp = fmaxf(logf(p), -100.0f);
  float lq = fmaxf(logf(1.0f-p), -100.0f);
  return -(t*lp + (1.0f-t)*lq);
}

// ---------------------------------------------------------------- init
// Only mask/noobj need initialization (read for every cell).
// tx/ty/tw/th/clsm are read ONLY where mask==1, and build writes those.
__global__ __launch_bounds__(256) void yolo_init(unsigned* __restrict__ mask_w,
                                                 unsigned* __restrict__ noobj_w){
  int i = blockIdx.x*blockDim.x + threadIdx.x;
  int stride = gridDim.x*blockDim.x;
  const int words = NCELL/4;
  for (int j=i; j<words; j+=stride){
    mask_w[j]  = 0u;           // mask bytes = 0
    noobj_w[j] = 0x01010101u;  // noobj bytes = 1
  }
}

// ---------------------------------------------------------------- build targets
// One thread per batch b; sequential over t => np "last write wins" semantics
// within a batch; cells of different batches are disjoint (cell encodes b).
__global__ void yolo_build(const float* __restrict__ tgt,
    unsigned char* __restrict__ mask8, unsigned char* __restrict__ noobj8,
    float* __restrict__ tx, float* __restrict__ ty,
    float* __restrict__ tw, float* __restrict__ th,
    unsigned* __restrict__ clsm){
  __shared__ int s_cell[Bn][Tn];
  __shared__ int s_cls [Bn][Tn];
  int b = threadIdx.x;
  if (b >= Bn) return;
  const float aw[3] = {1.25f, 2.0f, 4.125f};   // ANCHORS / STRIDE, exact in fp32
  const float ah[3] = {1.625f, 3.75f, 2.875f};

  for (int t=0; t<Tn; ++t){
    const float* tp = tgt + (size_t)(b*Tn + t)*5;
    float c0=tp[0], c1=tp[1], c2=tp[2], c3=tp[3], c4=tp[4];
    bool valid = (c0+c1+c2+c3+c4) != 0.0f;
    float gx=c1*(float)Wn, gy=c2*(float)Hn, gw=c3*(float)Wn, gh=c4*(float)Hn;
    int gi=(int)gx, gj=(int)gy;                 // trunc toward zero = astype(int32)
    float A1=(gw+1.0f)*(gh+1.0f);
    int best=0; float biou=-1.0f; float ious[3];
    #pragma unroll
    for (int a=0;a<3;++a){
      float iw=fmaxf(fminf(gw,aw[a])+1.0f, 0.0f);
      float ih=fmaxf(fminf(gh,ah[a])+1.0f, 0.0f);
      float inter=iw*ih;
      float A2=(aw[a]+1.0f)*(ah[a]+1.0f);
      float iou=inter/(A1+A2-inter+1e-16f);     // same assoc order as jnp
      ious[a]=iou;
      if (iou>biou){biou=iou;best=a;}           // strict > => first-occurrence argmax
    }
    if (valid){
      #pragma unroll
      for (int a=0;a<3;++a){
        if (ious[a] > 0.5f){
          // replicate flat-index mode='drop' semantics: drop only if outside [0,NCELL)
          long idx = (((long)(b*An+a)*Hn + gj)*Wn + gi);
          if (idx >= 0 && idx < (long)NCELL) noobj8[idx] = 0;
        }
      }
    }
    bool ok = valid && (gj<Hn) && (gi<Wn);
    int cellrec = -1;
    if (ok){
      int cell = ((b*An+best)*Hn + gj)*Wn + gi;
      mask8[cell] = 1;
      tx[cell] = gx - (float)gi;
      ty[cell] = gy - (float)gj;
      tw[cell] = logf(gw/aw[best] + 1e-16f);
      th[cell] = logf(gh/ah[best] + 1e-16f);
      cellrec = cell;
    }
    s_cell[b][t] = cellrec;
    s_cls [b][t] = (int)c0;
  }
  // tcls is a UNION of set-1 scatters (colliding cells may get 2 class bits).
  // Pass A: zero the 3 class words of every touched cell (so clsm needs no global init).
  for (int t=0;t<Tn;++t){
    int cell = s_cell[b][t];
    if (cell >= 0){
      clsm[3*(size_t)cell+0]=0u; clsm[3*(size_t)cell+1]=0u; clsm[3*(size_t)cell+2]=0u;
    }
  }
  // Pass B: OR in the class bits (same thread -> ordered after pass A).
  for (int t=0;t<Tn;++t){
    int cell = s_cell[b][t];
    int ci   = s_cls [b][t];
    if (cell >= 0 && ci >= 0 && ci < Cn){
      clsm[3*(size_t)cell + (ci>>5)] |= (1u << (ci & 31));
    }
  }
}

// ---------------------------------------------------------------- main loss
// For mask==0 cells every masked term is EXACTLY 0 under clip-then-multiply,
// so only the conf channel (ch 4) is read for ~all cells. Class logits +
// ch0..3 + tx/ty/tw/th/clsm are gathered only at the ~800 masked cells.
__global__ __launch_bounds__(256) void yolo_main(const float* __restrict__ in,
    const unsigned char* __restrict__ mask8, const unsigned char* __restrict__ noobj8,
    const float* __restrict__ tx, const float* __restrict__ ty,
    const float* __restrict__ tw, const float* __restrict__ th,
    const unsigned* __restrict__ clsm, float* __restrict__ partials){
  int i  = blockIdx.x*NTHREADS + threadIdx.x;      // exact grid, no bounds check
  int w  = i % Wn;
  int t1 = i / Wn;
  int h  = t1 % Hn;
  int ba = t1 / Hn;                                 // b*A + a ; channel base = ba*85
  const float* p = in + (size_t)ba*(5+Cn)*HWn + (size_t)h*Wn + w;

  float conf = sigmoidf_(p[(size_t)4*HWn]);
  float m  = (float)mask8[i];
  float nm = (float)noobj8[i];

  float v[9];
  v[0]=m; v[1]=nm;
  v[2]=0.f; v[3]=0.f; v[4]=0.f; v[5]=0.f; v[6]=0.f; v[8]=0.f;
  v[7] = (nm != 0.0f) ? bcef_(conf, 0.0f) : 0.0f;   // bce(conf*noobj, 0)

  if (m != 0.0f){                                   // m == 1 exactly
    float p0=p[0], p1=p[(size_t)HWn], p2=p[(size_t)2*HWn], p3=p[(size_t)3*HWn];
    float x=sigmoidf_(p0), y=sigmoidf_(p1);
    v[2] = bcef_(x, tx[i]);
    v[3] = bcef_(y, ty[i]);
    float dw = p2 - tw[i]; v[4] = dw*dw;
    float dh = p3 - th[i]; v[5] = dh*dh;
    v[6] = bcef_(conf, 1.0f);                       // bce(conf*mask, mask)
    unsigned cw0=clsm[3*(size_t)i], cw1=clsm[3*(size_t)i+1], cw2=clsm[3*(size_t)i+2];
    float s8 = 0.0f;
    for (int c=0;c<Cn;++c){
      float pc = p[(size_t)(5+c)*HWn];
      float s  = sigmoidf_(pc);
      unsigned wd = (c<32)?cw0:((c<64)?cw1:cw2);
      float tt = ((wd >> (c&31)) & 1u) ? 1.0f : 0.0f;
      s8 += bcef_(s, tt);
    }
    v[8] = s8;
  }

  // block reduction: wave64 shuffle, then LDS across 4 waves
  __shared__ float sm[4][9];
  #pragma unroll
  for (int k=0;k<9;++k){
    float val = v[k];
    for (int off=32; off>0; off>>=1) val += __shfl_down(val, off, 64);
    v[k] = val;
  }
  int lane = threadIdx.x & 63, wid = threadIdx.x >> 6;
  if (lane == 0){
    #pragma unroll
    for (int k=0;k<9;++k) sm[wid][k] = v[k];
  }
  __syncthreads();
  if (threadIdx.x == 0){
    #pragma unroll
    for (int k=0;k<9;++k)
      partials[(size_t)blockIdx.x*9 + k] = sm[0][k]+sm[1][k]+sm[2][k]+sm[3][k];
  }
}

// ---------------------------------------------------------------- finalize
// Deterministic double-precision reduction of 1083 block partials.
__global__ __launch_bounds__(256) void yolo_final(const float* __restrict__ partials,
                                                  float* __restrict__ out){
  double acc[9] = {0,0,0,0,0,0,0,0,0};
  for (int b = threadIdx.x; b < NBLK; b += 256){
    #pragma unroll
    for (int k=0;k<9;++k) acc[k] += (double)partials[(size_t)b*9 + k];
  }
  __shared__ double sm[4][9];
  #pragma unroll
  for (int k=0;k<9;++k){
    double v = acc[k];
    for (int off=32; off>0; off>>=1) v += __shfl_down(v, off, 64);
    acc[k] = v;
  }
  int lane = threadIdx.x & 63, wid = threadIdx.x >> 6;
  if (lane == 0){
    #pragma unroll
    for (int k=0;k<9;++k) sm[wid][k] = acc[k];
  }
  __syncthreads();
  if (threadIdx.x == 0){
    double S[9];
    #pragma unroll
    for (int k=0;k<9;++k) S[k] = sm[0][k]+sm[1][k]+sm[2][k]+sm[3][k];
    const double Nf = (double)NCELL;
    double n_m  = S[0];
    double n_nm = S[1];
    double lx = S[2]/Nf/n_m;
    double ly = S[3]/Nf/n_m;
    double lw = S[4]/Nf/n_m;
    double lh = S[5]/Nf/n_m;
    double lconf = S[6]/Nf/n_m + 0.5*S[7]/Nf/n_nm;
    double lcls  = S[8]/(n_m*(double)Cn)/n_m;
    double loss  = 2.5*(lx+ly) + 2.5*(lw+lh) + lconf + lcls;
    out[0]=(float)loss; out[1]=(float)lx; out[2]=(float)ly;
    out[3]=(float)lw;   out[4]=(float)lh; out[5]=(float)lconf; out[6]=(float)lcls;
  }
}

extern "C" void kernel_launch(void* const* d_in, const int* in_sizes, int n_in,
                              void* d_out, int out_size, void* d_ws, size_t ws_size,
                              hipStream_t stream) {
  const float* in  = (const float*)d_in[0];   // (B, 255, 76, 76) fp32
  const float* tgt = (const float*)d_in[1];   // (B, 50, 5) fp32
  float* out = (float*)d_out;                 // 7 scalars

  // workspace layout (bytes): 4*N f32 | 3*N u32 | N u8 | N u8 | NBLK*9 f32
  char* ws = (char*)d_ws;
  float* tx = (float*)ws;
  float* ty = tx + NCELL;
  float* tw = ty + NCELL;
  float* th = tw + NCELL;
  unsigned* clsm = (unsigned*)(th + NCELL);            // 3*NCELL words
  unsigned char* mask8  = (unsigned char*)(clsm + 3*(size_t)NCELL);
  unsigned char* noobj8 = mask8 + NCELL;
  float* partials = (float*)(noobj8 + NCELL);          // offset 30*NCELL, 4B aligned
  // total: 30*NCELL + NBLK*9*4 ≈ 8.36 MB

  yolo_init <<<256, 256, 0, stream>>>((unsigned*)mask8, (unsigned*)noobj8);
  yolo_build<<<1, 64, 0, stream>>>(tgt, mask8, noobj8, tx, ty, tw, th, clsm);
  yolo_main <<<NBLK, NTHREADS, 0, stream>>>(in, mask8, noobj8, tx, ty, tw, th, clsm, partials);
  yolo_final<<<1, 256, 0, stream>>>(partials, out);
}

// Round 2
// 176.690 us; speedup vs baseline: 1.3846x; 1.3846x over previous
//
#include <hip/hip_runtime.h>

// Problem constants (must match reference)
#define Bn 16
#define An 3
#define Cn 80
#define Hn 76
#define Wn 76
#define Tn 50
#define HWn (Hn*Wn)                 // 5776
#define NCELL (Bn*An*Hn*Wn)         // 277248
#define NTHREADS 256
#define NBLK (NCELL/NTHREADS)       // 1083 (exact)
#define NCORR 64                    // correction blocks
#define NTOT (NBLK + NCORR)         // 1147
#define NTGT (Bn*Tn)                // 800 targets
#define NUNIT_W (NTGT*85)           // 68000 winner-channel units
#define NUNIT (NUNIT_W + NTGT*3)    // + 2400 noobj entries = 70400

static_assert(NCELL % NTHREADS == 0, "grid must be exact");

__device__ __forceinline__ float sigmoidf_(float z){ return 1.0f/(1.0f+expf(-z)); }

// bce(p,t) = -( t*max(log p, -100) + (1-t)*max(log(1-p), -100) )
// clip BEFORE multiply: 0 * (-100) = 0, never 0 * -inf.  (matches reference exactly)
__device__ __forceinline__ float bcef_(float p, float t){
  float lp = fmaxf(logf(p), -100.0f);
  float lq = fmaxf(logf(1.0f-p), -100.0f);
  return -(t*lp + (1.0f-t)*lq);
}

// ---------------------------------------------------------------- fused main
// Blocks [0, NBLK): streaming — every cell contributes bce(sigmoid(conf),0) to S7.
//   (all masked loss terms are EXACTLY 0 for unmasked cells under clip-then-mult,
//    and noobj=1 cells' conf term is exactly bce(conf,0) — so no mask arrays needed)
// Blocks [NBLK, NTOT): correction — redo the cheap 800-target build in LDS,
//   dedup (last-write-wins winners for mask terms; first-occurrence reps for
//   noobj-zero set), then process a slice of the scattered correction units:
//     winner units  (tg,c): add x/y/w/h/conf_obj/cls terms for masked cells
//     noobj units   (tg,a): subtract bce(conf,0) for noobj==0 cells, n_nm -= 1
__global__ __launch_bounds__(256) void yolo_main(
    const float* __restrict__ in, const float* __restrict__ tgt,
    float* __restrict__ partials){
  __shared__ int      s_cell[NTGT];      // ok ? cell : -1
  __shared__ int      s_cls [NTGT];      // class id
  __shared__ float    s_tx[NTGT], s_ty[NTGT], s_tw[NTGT], s_th[NTGT];
  __shared__ unsigned s_clsu[NTGT][3];   // class-bit union for winners
  __shared__ int      s_nidx[NTGT*3];    // noobj-zero candidate flat idx or -1
  __shared__ unsigned char s_win[NTGT];  // last-write-wins winner flag
  __shared__ float    sm[4][9];

  const int tid = threadIdx.x;
  float v[9] = {0.f,0.f,0.f,0.f,0.f,0.f,0.f,0.f,0.f};

  if (blockIdx.x < NBLK){
    // ---- streaming path: 1 coalesced conf load per cell
    int i  = blockIdx.x*NTHREADS + tid;
    int ba = i / HWn, off = i % HWn;
    float z = in[((size_t)ba*85 + 4)*HWn + off];
    v[7] = bcef_(sigmoidf_(z), 0.0f);
  } else {
    // ---- correction path
    const int bi = blockIdx.x - NBLK;           // 0..NCORR-1
    const float aw[3] = {1.25f, 2.0f, 4.125f};  // ANCHORS/STRIDE, exact fp32
    const float ah[3] = {1.625f, 3.75f, 2.875f};

    // Phase A: per-target compute (identical fp32 ops to reference)
    for (int tg = tid; tg < NTGT; tg += NTHREADS){
      int b = tg / Tn;
      const float* tp = tgt + (size_t)tg*5;
      float c0=tp[0], c1=tp[1], c2=tp[2], c3=tp[3], c4=tp[4];
      bool valid = (c0+c1+c2+c3+c4) != 0.0f;
      float gx=c1*(float)Wn, gy=c2*(float)Hn, gw=c3*(float)Wn, gh=c4*(float)Hn;
      int gi=(int)gx, gj=(int)gy;               // trunc = astype(int32)
      float A1=(gw+1.0f)*(gh+1.0f);
      int best=0; float biou=-1.0f; float ious[3];
      #pragma unroll
      for (int a=0;a<3;++a){
        float iw=fmaxf(fminf(gw,aw[a])+1.0f, 0.0f);
        float ih=fmaxf(fminf(gh,ah[a])+1.0f, 0.0f);
        float inter=iw*ih;
        float A2=(aw[a]+1.0f)*(ah[a]+1.0f);
        float iou=inter/(A1+A2-inter+1e-16f);   // same assoc order as reference
        ious[a]=iou;
        if (iou>biou){biou=iou;best=a;}         // strict > = first-occurrence argmax
      }
      #pragma unroll
      for (int a=0;a<3;++a){
        long idxa = (((long)(b*An+a)*Hn + gj)*Wn + gi);
        bool nz = valid && (ious[a] > 0.5f) && idxa >= 0 && idxa < (long)NCELL;
        s_nidx[tg*3+a] = nz ? (int)idxa : -1;
      }
      bool ok = valid && (gj < Hn) && (gi < Wn) && gi >= 0 && gj >= 0;
      int cell = ((b*An+best)*Hn + gj)*Wn + gi;
      s_cell[tg] = ok ? cell : -1;
      s_cls [tg] = (int)c0;
      s_tx[tg] = gx - (float)gi;
      s_ty[tg] = gy - (float)gj;
      s_tw[tg] = logf(gw/aw[best] + 1e-16f);
      s_th[tg] = logf(gh/ah[best] + 1e-16f);
    }
    __syncthreads();

    // Phase A2: winner flags (last write wins within batch; batches disjoint)
    //           + class-bit union over ALL same-cell ok targets of the batch
    for (int tg = tid; tg < NTGT; tg += NTHREADS){
      int cell = s_cell[tg];
      unsigned char win = 0;
      if (cell >= 0){
        int b = tg / Tn, e = (b+1)*Tn;
        win = 1;
        for (int t2 = tg+1; t2 < e; ++t2)
          if (s_cell[t2] == cell){ win = 0; break; }
        if (win){
          unsigned u0=0,u1=0,u2=0;
          for (int t2 = b*Tn; t2 < e; ++t2){
            if (s_cell[t2] == cell){
              int cc = s_cls[t2];
              if (cc >= 0 && cc < Cn){
                if (cc < 32) u0 |= (1u<<cc);
                else if (cc < 64) u1 |= (1u<<(cc-32));
                else u2 |= (1u<<(cc-64));
              }
            }
          }
          s_clsu[tg][0]=u0; s_clsu[tg][1]=u1; s_clsu[tg][2]=u2;
        }
      }
      s_win[tg] = win;
    }
    __syncthreads();

    // Phase B: process unit slice (scattered gathers from input)
    for (int u = bi*NTHREADS + tid; u < NUNIT; u += NCORR*NTHREADS){
      if (u < NUNIT_W){
        int tg = u / 85, c = u % 85;
        if (s_win[tg]){
          int q = s_cell[tg];
          int ba = q / HWn, off = q % HWn;
          float z = in[((size_t)ba*85 + c)*HWn + off];
          if      (c==0) v[2] += bcef_(sigmoidf_(z), s_tx[tg]);
          else if (c==1) v[3] += bcef_(sigmoidf_(z), s_ty[tg]);
          else if (c==2){ float d = z - s_tw[tg]; v[4] += d*d; }
          else if (c==3){ float d = z - s_th[tg]; v[5] += d*d; }
          else if (c==4){ v[6] += bcef_(sigmoidf_(z), 1.0f); v[0] += 1.0f; }
          else {
            int cc = c - 5;
            float tt = ((s_clsu[tg][cc>>5] >> (cc&31)) & 1u) ? 1.0f : 0.0f;
            v[8] += bcef_(sigmoidf_(z), tt);
          }
        }
      } else {
        int e = u - NUNIT_W;               // 0..2399, batch = e/150
        int idx = s_nidx[e];
        if (idx >= 0){
          bool rep = true;                 // first occurrence within batch
          for (int e2 = (e/(Tn*3))*(Tn*3); e2 < e; ++e2)
            if (s_nidx[e2] == idx){ rep = false; break; }
          if (rep){
            int ba = idx / HWn, off = idx % HWn;
            float z = in[((size_t)ba*85 + 4)*HWn + off];
            v[7] -= bcef_(sigmoidf_(z), 0.0f);
            v[1] -= 1.0f;                  // n_nm deficit
          }
        }
      }
    }
  }

  // block reduction: wave64 shuffle, then LDS across 4 waves
  #pragma unroll
  for (int k=0;k<9;++k){
    float val = v[k];
    for (int off=32; off>0; off>>=1) val += __shfl_down(val, off, 64);
    v[k] = val;
  }
  int lane = tid & 63, wid = tid >> 6;
  if (lane == 0){
    #pragma unroll
    for (int k=0;k<9;++k) sm[wid][k] = v[k];
  }
  __syncthreads();
  if (tid == 0){
    #pragma unroll
    for (int k=0;k<9;++k)
      partials[(size_t)blockIdx.x*9 + k] = sm[0][k]+sm[1][k]+sm[2][k]+sm[3][k];
  }
}

// ---------------------------------------------------------------- finalize
// Deterministic double-precision reduction of NTOT block partials.
__global__ __launch_bounds__(256) void yolo_final(const float* __restrict__ partials,
                                                  float* __restrict__ out){
  double acc[9] = {0,0,0,0,0,0,0,0,0};
  for (int b = threadIdx.x; b < NTOT; b += 256){
    #pragma unroll
    for (int k=0;k<9;++k) acc[k] += (double)partials[(size_t)b*9 + k];
  }
  __shared__ double sm[4][9];
  #pragma unroll
  for (int k=0;k<9;++k){
    double v = acc[k];
    for (int off=32; off>0; off>>=1) v += __shfl_down(v, off, 64);
    acc[k] = v;
  }
  int lane = threadIdx.x & 63, wid = threadIdx.x >> 6;
  if (lane == 0){
    #pragma unroll
    for (int k=0;k<9;++k) sm[wid][k] = acc[k];
  }
  __syncthreads();
  if (threadIdx.x == 0){
    double S[9];
    #pragma unroll
    for (int k=0;k<9;++k) S[k] = sm[0][k]+sm[1][k]+sm[2][k]+sm[3][k];
    const double Nf = (double)NCELL;
    double n_m  = S[0];
    double n_nm = (double)NCELL + S[1];   // S[1] is the (negative) deficit
    double lx = S[2]/Nf/n_m;
    double ly = S[3]/Nf/n_m;
    double lw = S[4]/Nf/n_m;
    double lh = S[5]/Nf/n_m;
    double lconf = S[6]/Nf/n_m + 0.5*S[7]/Nf/n_nm;
    double lcls  = S[8]/(n_m*(double)Cn)/n_m;
    double loss  = 2.5*(lx+ly) + 2.5*(lw+lh) + lconf + lcls;
    out[0]=(float)loss; out[1]=(float)lx; out[2]=(float)ly;
    out[3]=(float)lw;   out[4]=(float)lh; out[5]=(float)lconf; out[6]=(float)lcls;
  }
}

extern "C" void kernel_launch(void* const* d_in, const int* in_sizes, int n_in,
                              void* d_out, int out_size, void* d_ws, size_t ws_size,
                              hipStream_t stream) {
  const float* in  = (const float*)d_in[0];   // (B, 255, 76, 76) fp32
  const float* tgt = (const float*)d_in[1];   // (B, 50, 5) fp32
  float* out = (float*)d_out;                 // 7 scalars

  float* partials = (float*)d_ws;             // NTOT*9 floats ≈ 41 KB

  yolo_main <<<NTOT, NTHREADS, 0, stream>>>(in, tgt, partials);
  yolo_final<<<1, 256, 0, stream>>>(partials, out);
}

// Round 3
// 174.239 us; speedup vs baseline: 1.4040x; 1.0141x over previous
//
#include <hip/hip_runtime.h>

// Problem constants (must match reference)
#define Bn 16
#define An 3
#define Cn 80
#define Hn 76
#define Wn 76
#define Tn 50
#define HWn (Hn*Wn)                 // 5776
#define NCELL (Bn*An*Hn*Wn)         // 277248
#define NTHREADS 256
#define NSTREAM (NCELL/NTHREADS)    // 1083 streaming blocks (exact)
#define NCORR 138                   // correction blocks (dispatched FIRST)
#define NTOT (NSTREAM + NCORR)      // 1221
#define NTGT (Bn*Tn)                // 800 targets
#define NNO  (NTGT*3)               // 2400 noobj candidates
#define NUNIT_W (85*NTGT)           // 68000 winner-channel units (c-major!)
#define NUNIT (NUNIT_W + NNO)       // 70400

static_assert(NCELL % NTHREADS == 0, "grid must be exact");

__device__ __forceinline__ float sigmoidf_(float z){ return 1.0f/(1.0f+expf(-z)); }

// bce(p,t) = -( t*max(log p, -100) + (1-t)*max(log(1-p), -100) )
// clip BEFORE multiply: 0 * (-100) = 0, never 0 * -inf.  (matches reference exactly)
__device__ __forceinline__ float bcef_(float p, float t){
  float lp = fmaxf(logf(p), -100.0f);
  float lq = fmaxf(logf(1.0f-p), -100.0f);
  return -(t*lp + (1.0f-t)*lq);
}

__device__ __forceinline__ int cell_of(int pc){ return pc & 0x7FFFF; }  // 19 bits
__device__ __forceinline__ int cls_of (int pc){ return (pc >> 19) & 0x7F; }

// ---------------------------------------------------------------- fused main
// Blocks [0, NCORR): correction — rebuild the 800-target tables in LDS with
//   BRANCHLESS dedup scans (no break => pipelined ds_reads), then process a
//   c-major slice of scattered correction units (wave-uniform branches).
// Blocks [NCORR, NTOT): streaming — every cell contributes bce(sig(conf),0);
//   all masked terms are exactly 0 for unmasked cells under clip-then-mult.
__global__ __launch_bounds__(256) void yolo_main(
    const float* __restrict__ in, const float* __restrict__ tgt,
    float* __restrict__ partials){
  __shared__ int           s_cell[NTGT];     // ok ? (cell | cls<<19) : -1
  __shared__ unsigned      s_clsu[NTGT][3];  // class-bit union (winners only)
  __shared__ int           s_nidx[NNO];      // noobj-zero candidate idx or -1
  __shared__ unsigned char s_win [NTGT];     // last-write-wins winner flag
  __shared__ unsigned char s_nrep[NNO];      // first-occurrence rep flag
  __shared__ float         sm[4][9];

  const int tid = threadIdx.x;
  float v[9] = {0.f,0.f,0.f,0.f,0.f,0.f,0.f,0.f,0.f};

  if (blockIdx.x >= NCORR){
    // ---- streaming path: 1 coalesced conf load per cell
    int i  = (blockIdx.x - NCORR)*NTHREADS + tid;
    int ba = i / HWn, off = i % HWn;
    float z = in[((size_t)ba*85 + 4)*HWn + off];
    v[7] = bcef_(sigmoidf_(z), 0.0f);
  } else {
    const int bi = blockIdx.x;                  // 0..NCORR-1
    const float aw[3] = {1.25f, 2.0f, 4.125f};  // ANCHORS/STRIDE, exact fp32
    const float ah[3] = {1.625f, 3.75f, 2.875f};

    // Phase A: per-target compute (identical fp32 ops to reference)
    for (int tg = tid; tg < NTGT; tg += NTHREADS){
      int b = tg / Tn;
      const float* tp = tgt + (size_t)tg*5;
      float c0=tp[0], c1=tp[1], c2=tp[2], c3=tp[3], c4=tp[4];
      bool valid = (c0+c1+c2+c3+c4) != 0.0f;
      float gx=c1*(float)Wn, gy=c2*(float)Hn, gw=c3*(float)Wn, gh=c4*(float)Hn;
      int gi=(int)gx, gj=(int)gy;               // trunc = astype(int32)
      float A1=(gw+1.0f)*(gh+1.0f);
      int best=0; float biou=-1.0f; float ious[3];
      #pragma unroll
      for (int a=0;a<3;++a){
        float iw=fmaxf(fminf(gw,aw[a])+1.0f, 0.0f);
        float ih=fmaxf(fminf(gh,ah[a])+1.0f, 0.0f);
        float inter=iw*ih;
        float A2=(aw[a]+1.0f)*(ah[a]+1.0f);
        float iou=inter/(A1+A2-inter+1e-16f);   // same assoc order as reference
        ious[a]=iou;
        if (iou>biou){biou=iou;best=a;}         // strict > = first-occurrence argmax
      }
      #pragma unroll
      for (int a=0;a<3;++a){
        long idxa = (((long)(b*An+a)*Hn + gj)*Wn + gi);
        bool nz = valid && (ious[a] > 0.5f) && idxa >= 0 && idxa < (long)NCELL;
        s_nidx[tg*3+a] = nz ? (int)idxa : -1;
      }
      bool ok = valid && (gj < Hn) && (gi < Wn) && gi >= 0 && gj >= 0;
      int cell = ((b*An+best)*Hn + gj)*Wn + gi;
      int ci   = (int)c0;
      int ci7  = (ci >= 0 && ci < Cn) ? ci : 127;   // sentinel: contributes no bit
      s_cell[tg] = ok ? (cell | (ci7 << 19)) : -1;
    }
    __syncthreads();

    // Phase A2a: winner flags — BRANCHLESS suffix scan (last write wins per batch)
    for (int tg = tid; tg < NTGT; tg += NTHREADS){
      int pc = s_cell[tg];
      int cell = cell_of(pc);
      int win = (pc >= 0) ? 1 : 0;
      int e = ((tg/Tn)+1)*Tn;
      for (int t2 = tg+1; t2 < e; ++t2){        // no break -> pipelined
        int pc2 = s_cell[t2];
        win &= !((pc2 >= 0) & (cell_of(pc2) == cell));
      }
      s_win[tg] = (unsigned char)win;
      if (win){                                 // class-bit union over batch
        unsigned u0=0,u1=0,u2=0;
        int s = (tg/Tn)*Tn;
        for (int t2 = s; t2 < e; ++t2){
          int pc2 = s_cell[t2];
          if ((pc2 >= 0) & (cell_of(pc2) == cell)){
            int cc = cls_of(pc2);
            if      (cc < 32) u0 |= (1u<<cc);
            else if (cc < 64) u1 |= (1u<<(cc-32));
            else if (cc < Cn) u2 |= (1u<<(cc-64));
          }
        }
        s_clsu[tg][0]=u0; s_clsu[tg][1]=u1; s_clsu[tg][2]=u2;
      }
    }
    // Phase A2b: noobj rep flags — BRANCHLESS prefix scan (first occurrence per batch)
    for (int e = tid; e < NNO; e += NTHREADS){
      int idx = s_nidx[e];
      int rep = (idx >= 0) ? 1 : 0;
      int s = (e/(Tn*3))*(Tn*3);
      for (int e2 = s; e2 < e; ++e2)            // no break -> pipelined
        rep &= (s_nidx[e2] != idx);
      s_nrep[e] = (unsigned char)rep;
    }
    __syncthreads();

    // Phase B: c-major unit slice (wave-uniform branch on c)
    for (int u = bi*NTHREADS + tid; u < NUNIT; u += NCORR*NTHREADS){
      if (u < NUNIT_W){
        int c = u / NTGT, tg = u - c*NTGT;      // wave: same c, consecutive tg
        if (s_win[tg]){
          int pc = s_cell[tg];
          int q  = cell_of(pc);
          int ba = q / HWn, off = q % HWn;
          float z = in[((size_t)ba*85 + c)*HWn + off];
          if (c >= 5){
            int cc = c - 5;
            float tt = ((s_clsu[tg][cc>>5] >> (cc&31)) & 1u) ? 1.0f : 0.0f;
            v[8] += bcef_(sigmoidf_(z), tt);
          } else if (c == 4){
            v[6] += bcef_(sigmoidf_(z), 1.0f); v[0] += 1.0f;
          } else {
            // recompute tx/ty/tw/th from tgt (identical fp32 ops to reference)
            const float* tp = tgt + (size_t)tg*5;
            float gx=tp[1]*(float)Wn, gy=tp[2]*(float)Hn;
            float gw=tp[3]*(float)Wn, gh=tp[4]*(float)Hn;
            int gi=(int)gx, gj=(int)gy;
            float A1=(gw+1.0f)*(gh+1.0f);
            int best=0; float biou=-1.0f;
            const float aw2[3] = {1.25f, 2.0f, 4.125f};
            const float ah2[3] = {1.625f, 3.75f, 2.875f};
            #pragma unroll
            for (int a=0;a<3;++a){
              float iw=fmaxf(fminf(gw,aw2[a])+1.0f, 0.0f);
              float ih=fmaxf(fminf(gh,ah2[a])+1.0f, 0.0f);
              float inter=iw*ih;
              float A2=(aw2[a]+1.0f)*(ah2[a]+1.0f);
              float iou=inter/(A1+A2-inter+1e-16f);
              if (iou>biou){biou=iou;best=a;}
            }
            if      (c==0) v[2] += bcef_(sigmoidf_(z), gx - (float)gi);
            else if (c==1) v[3] += bcef_(sigmoidf_(z), gy - (float)gj);
            else if (c==2){ float d = z - logf(gw/aw2[best] + 1e-16f); v[4] += d*d; }
            else          { float d = z - logf(gh/ah2[best] + 1e-16f); v[5] += d*d; }
          }
        }
      } else {
        int e = u - NUNIT_W;
        int idx = s_nidx[e];
        if (idx >= 0 && s_nrep[e]){
          int ba = idx / HWn, off = idx % HWn;
          float z = in[((size_t)ba*85 + 4)*HWn + off];
          v[7] -= bcef_(sigmoidf_(z), 0.0f);    // cancel streaming contribution
          v[1] -= 1.0f;                          // n_nm deficit
        }
      }
    }
  }

  // block reduction: wave64 shuffle, then LDS across 4 waves
  #pragma unroll
  for (int k=0;k<9;++k){
    float val = v[k];
    for (int off=32; off>0; off>>=1) val += __shfl_down(val, off, 64);
    v[k] = val;
  }
  int lane = tid & 63, wid = tid >> 6;
  if (lane == 0){
    #pragma unroll
    for (int k=0;k<9;++k) sm[wid][k] = v[k];
  }
  __syncthreads();
  if (tid == 0){
    #pragma unroll
    for (int k=0;k<9;++k)
      partials[(size_t)blockIdx.x*9 + k] = sm[0][k]+sm[1][k]+sm[2][k]+sm[3][k];
  }
}

// ---------------------------------------------------------------- finalize
// Deterministic double-precision reduction of NTOT block partials.
__global__ __launch_bounds__(256) void yolo_final(const float* __restrict__ partials,
                                                  float* __restrict__ out){
  double acc[9] = {0,0,0,0,0,0,0,0,0};
  for (int b = threadIdx.x; b < NTOT; b += 256){
    #pragma unroll
    for (int k=0;k<9;++k) acc[k] += (double)partials[(size_t)b*9 + k];
  }
  __shared__ double sm[4][9];
  #pragma unroll
  for (int k=0;k<9;++k){
    double v = acc[k];
    for (int off=32; off>0; off>>=1) v += __shfl_down(v, off, 64);
    acc[k] = v;
  }
  int lane = threadIdx.x & 63, wid = threadIdx.x >> 6;
  if (lane == 0){
    #pragma unroll
    for (int k=0;k<9;++k) sm[wid][k] = acc[k];
  }
  __syncthreads();
  if (threadIdx.x == 0){
    double S[9];
    #pragma unroll
    for (int k=0;k<9;++k) S[k] = sm[0][k]+sm[1][k]+sm[2][k]+sm[3][k];
    const double Nf = (double)NCELL;
    double n_m  = S[0];
    double n_nm = (double)NCELL + S[1];   // S[1] is the (negative) deficit
    double lx = S[2]/Nf/n_m;
    double ly = S[3]/Nf/n_m;
    double lw = S[4]/Nf/n_m;
    double lh = S[5]/Nf/n_m;
    double lconf = S[6]/Nf/n_m + 0.5*S[7]/Nf/n_nm;
    double lcls  = S[8]/(n_m*(double)Cn)/n_m;
    double loss  = 2.5*(lx+ly) + 2.5*(lw+lh) + lconf + lcls;
    out[0]=(float)loss; out[1]=(float)lx; out[2]=(float)ly;
    out[3]=(float)lw;   out[4]=(float)lh; out[5]=(float)lconf; out[6]=(float)lcls;
  }
}

extern "C" void kernel_launch(void* const* d_in, const int* in_sizes, int n_in,
                              void* d_out, int out_size, void* d_ws, size_t ws_size,
                              hipStream_t stream) {
  const float* in  = (const float*)d_in[0];   // (B, 255, 76, 76) fp32
  const float* tgt = (const float*)d_in[1];   // (B, 50, 5) fp32
  float* out = (float*)d_out;                 // 7 scalars

  float* partials = (float*)d_ws;             // NTOT*9 floats ≈ 44 KB

  yolo_main <<<NTOT, NTHREADS, 0, stream>>>(in, tgt, partials);
  yolo_final<<<1, 256, 0, stream>>>(partials, out);
}

// Round 4
// 136.707 us; speedup vs baseline: 1.7895x; 1.2745x over previous
//
#include <hip/hip_runtime.h>

// Problem constants (must match reference)
#define Bn 16
#define An 3
#define Cn 80
#define Hn 76
#define Wn 76
#define Tn 50
#define HWn (Hn*Wn)                 // 5776
#define NCELL (Bn*An*Hn*Wn)         // 277248
#define NTHREADS 256
#define NCPB 8                      // correction blocks per batch
#define NCORRTOT (Bn*NCPB)          // 128 correction blocks, dispatched FIRST
#define NSEG (Bn*An)                // 48 contiguous conf segments
#define NF4SEG (HWn/4)              // 1444 float4 per segment
#define NF4 (NSEG*NF4SEG)           // 69312 float4 units
#define NSB ((NF4 + NTHREADS - 1)/NTHREADS)   // 271 streaming blocks
#define NTOT (NCORRTOT + NSB)       // 399
#define NUNIT_W (85*Tn)             // 4250 winner units per batch (c-major)
#define NUNIT (NUNIT_W + Tn*An)     // 4400 incl. noobj candidates

static_assert(HWn % 4 == 0, "float4 path");

__device__ __forceinline__ float sigmoidf_(float z){ return 1.0f/(1.0f+expf(-z)); }

// bce(p,t) = -( t*max(log p, -100) + (1-t)*max(log(1-p), -100) )
// clip BEFORE multiply: 0 * (-100) = 0, never 0 * -inf.  (matches reference exactly)
__device__ __forceinline__ float bcef_(float p, float t){
  float lp = fmaxf(logf(p), -100.0f);
  float lq = fmaxf(logf(1.0f-p), -100.0f);
  return -(t*lp + (1.0f-t)*lq);
}

// ---------------------------------------------------------------- fused main
// Blocks [0, NCORRTOT): correction for batch b = blk&15, slice sub = blk>>4.
//   Wave 0 rebuilds the batch's 50-target tables ENTIRELY IN REGISTERS with
//   unrolled cross-lane loops (no LDS-latency-serialized scans — the R3
//   bottleneck), dumps ~2.5 KB tables to LDS; all 4 waves then process a
//   c-major slice of the 4400 scattered correction units.
// Blocks [NCORRTOT, NTOT): streaming — float4 over the conf channel; every
//   cell contributes bce(sigmoid(conf),0) to S7 (all masked terms are exactly
//   0 for unmasked cells under clip-then-multiply).
__global__ __launch_bounds__(256) void yolo_main(
    const float* __restrict__ in, const float* __restrict__ tgt,
    float* __restrict__ partials){
  __shared__ int           s_cell[Tn];
  __shared__ float         s_tx[Tn], s_ty[Tn], s_tw[Tn], s_th[Tn];
  __shared__ unsigned      s_clsu[Tn][3];
  __shared__ unsigned char s_win[Tn];
  __shared__ int           s_nidx[Tn*An];
  __shared__ unsigned char s_nrep[Tn*An];
  __shared__ float         sm[4][9];

  const int tid = threadIdx.x;

  if (blockIdx.x >= NCORRTOT){
    // ---------------- streaming path
    int id = (blockIdx.x - NCORRTOT)*NTHREADS + tid;
    float v7 = 0.0f;
    if (id < NF4){
      int seg = id / NF4SEG;
      int k   = id - seg*NF4SEG;
      const float4 z4 = ((const float4*)in)[(size_t)(seg*85+4)*NF4SEG + k];
      v7 = bcef_(sigmoidf_(z4.x),0.f) + bcef_(sigmoidf_(z4.y),0.f)
         + bcef_(sigmoidf_(z4.z),0.f) + bcef_(sigmoidf_(z4.w),0.f);
    }
    for (int off=32; off>0; off>>=1) v7 += __shfl_down(v7, off, 64);
    int lane = tid & 63, wid = tid >> 6;
    if (lane == 0) sm[wid][0] = v7;
    __syncthreads();
    if (tid == 0){
      float s7 = sm[0][0]+sm[1][0]+sm[2][0]+sm[3][0];
      float* p = partials + (size_t)blockIdx.x*9;
      p[0]=0.f;p[1]=0.f;p[2]=0.f;p[3]=0.f;p[4]=0.f;p[5]=0.f;p[6]=0.f;p[7]=s7;p[8]=0.f;
    }
    return;
  }

  // ---------------- correction path
  const int b   = blockIdx.x & (Bn-1);     // batch
  const int sub = blockIdx.x >> 4;         // 0..NCPB-1
  float v[9] = {0.f,0.f,0.f,0.f,0.f,0.f,0.f,0.f,0.f};

  if (tid < 64){
    // ---- register-resident build: lane t handles target t (t<50)
    const float aw[3] = {1.25f, 2.0f, 4.125f};   // ANCHORS/STRIDE, exact fp32
    const float ah[3] = {1.625f, 3.75f, 2.875f};
    const int t = tid;
    const bool tv = (t < Tn);
    int   mycell = -1, mycls = 127;
    int   n0 = -1, n1 = -1, n2 = -1;
    float ftx=0.f, fty=0.f, ftw=0.f, fth=0.f;
    if (tv){
      const float* tp = tgt + (size_t)(b*Tn + t)*5;
      float c0=tp[0], c1=tp[1], c2=tp[2], c3=tp[3], c4=tp[4];
      bool valid = (c0+c1+c2+c3+c4) != 0.0f;
      float gx=c1*(float)Wn, gy=c2*(float)Hn, gw=c3*(float)Wn, gh=c4*(float)Hn;
      int gi=(int)gx, gj=(int)gy;                // trunc = astype(int32)
      float A1=(gw+1.0f)*(gh+1.0f);
      int best=0; float biou=-1.0f; float ious[3];
      #pragma unroll
      for (int a=0;a<3;++a){
        float iw=fmaxf(fminf(gw,aw[a])+1.0f, 0.0f);
        float ih=fmaxf(fminf(gh,ah[a])+1.0f, 0.0f);
        float inter=iw*ih;
        float A2=(aw[a]+1.0f)*(ah[a]+1.0f);
        float iou=inter/(A1+A2-inter+1e-16f);    // same assoc order as reference
        ious[a]=iou;
        if (iou>biou){biou=iou;best=a;}          // strict > = first-occurrence argmax
      }
      {
        long i0 = (((long)(b*An+0)*Hn + gj)*Wn + gi);
        long i1 = (((long)(b*An+1)*Hn + gj)*Wn + gi);
        long i2 = (((long)(b*An+2)*Hn + gj)*Wn + gi);
        n0 = (valid && ious[0]>0.5f && i0>=0 && i0<(long)NCELL) ? (int)i0 : -1;
        n1 = (valid && ious[1]>0.5f && i1>=0 && i1<(long)NCELL) ? (int)i1 : -1;
        n2 = (valid && ious[2]>0.5f && i2>=0 && i2<(long)NCELL) ? (int)i2 : -1;
      }
      bool ok = valid && (gj<Hn) && (gi<Wn) && (gi>=0) && (gj>=0);
      if (ok) mycell = ((b*An+best)*Hn + gj)*Wn + gi;
      int ci = (int)c0;
      mycls = (ci>=0 && ci<Cn) ? ci : 127;       // sentinel: no bit contributed
      ftx = gx - (float)gi;  fty = gy - (float)gj;
      ftw = logf(gw/aw[best] + 1e-16f);
      fth = logf(gh/ah[best] + 1e-16f);
    }

    // ---- winner flag (last-write-wins) + class-bit union: unrolled readlanes
    unsigned win = (mycell >= 0) ? 1u : 0u;
    unsigned u0=0u, u1=0u, u2=0u;
    #pragma unroll
    for (int t2=0; t2<Tn; ++t2){
      int c2 = __shfl(mycell, t2, 64);
      int k2 = __shfl(mycls,  t2, 64);
      bool dup = (mycell >= 0) && (c2 == mycell);
      if (dup && (t2 > t)) win = 0u;
      if (dup){
        if      (k2 < 32) u0 |= (1u<<k2);
        else if (k2 < 64) u1 |= (1u<<(k2-32));
        else if (k2 < Cn) u2 |= (1u<<(k2-64));
      }
    }

    // ---- noobj first-occurrence rep flags: unrolled readlanes
    unsigned r0 = (n0>=0)?1u:0u, r1 = (n1>=0)?1u:0u, r2 = (n2>=0)?1u:0u;
    r1 &= (unsigned)(n1 != n0);
    r2 &= (unsigned)((n2 != n0) & (n2 != n1));
    #pragma unroll
    for (int t2=0; t2<Tn; ++t2){
      int s0 = __shfl(n0, t2, 64);
      int s1 = __shfl(n1, t2, 64);
      int s2 = __shfl(n2, t2, 64);
      if (t2 < t){
        r0 &= (unsigned)((n0!=s0) & (n0!=s1) & (n0!=s2));
        r1 &= (unsigned)((n1!=s0) & (n1!=s1) & (n1!=s2));
        r2 &= (unsigned)((n2!=s0) & (n2!=s1) & (n2!=s2));
      }
    }

    if (tv){
      s_cell[t] = mycell;
      s_win [t] = (unsigned char)win;
      s_clsu[t][0]=u0; s_clsu[t][1]=u1; s_clsu[t][2]=u2;
      s_tx[t]=ftx; s_ty[t]=fty; s_tw[t]=ftw; s_th[t]=fth;
      s_nidx[3*t  ]=n0; s_nidx[3*t+1]=n1; s_nidx[3*t+2]=n2;
      s_nrep[3*t  ]=(unsigned char)r0;
      s_nrep[3*t+1]=(unsigned char)r1;
      s_nrep[3*t+2]=(unsigned char)r2;
    }
  }
  __syncthreads();

  // ---- Phase B: c-major slice of this batch's units (scattered gathers)
  for (int u = sub*NTHREADS + tid; u < NUNIT; u += NCPB*NTHREADS){
    if (u < NUNIT_W){
      int c = u / Tn, t = u - c*Tn;            // wave: same c, consecutive t
      if (s_win[t]){
        int q  = s_cell[t];
        int ba = q / HWn, off = q - ba*HWn;
        float z = in[((size_t)ba*85 + c)*HWn + off];
        if (c >= 5){
          int cc = c - 5;
          float tt = ((s_clsu[t][cc>>5] >> (cc&31)) & 1u) ? 1.0f : 0.0f;
          v[8] += bcef_(sigmoidf_(z), tt);
        } else if (c == 4){
          v[6] += bcef_(sigmoidf_(z), 1.0f); v[0] += 1.0f;
        } else if (c == 0){
          v[2] += bcef_(sigmoidf_(z), s_tx[t]);
        } else if (c == 1){
          v[3] += bcef_(sigmoidf_(z), s_ty[t]);
        } else if (c == 2){
          float d = z - s_tw[t]; v[4] += d*d;
        } else {
          float d = z - s_th[t]; v[5] += d*d;
        }
      }
    } else {
      int e = u - NUNIT_W;
      int idx = s_nidx[e];
      if (idx >= 0 && s_nrep[e]){
        int ba = idx / HWn, off = idx - ba*HWn;
        float z = in[((size_t)ba*85 + 4)*HWn + off];
        v[7] -= bcef_(sigmoidf_(z), 0.0f);     // cancel streaming contribution
        v[1] -= 1.0f;                           // n_nm deficit
      }
    }
  }

  // block reduction: wave64 shuffle, then LDS across 4 waves
  #pragma unroll
  for (int k=0;k<9;++k){
    float val = v[k];
    for (int off=32; off>0; off>>=1) val += __shfl_down(val, off, 64);
    v[k] = val;
  }
  int lane = tid & 63, wid = tid >> 6;
  if (lane == 0){
    #pragma unroll
    for (int k=0;k<9;++k) sm[wid][k] = v[k];
  }
  __syncthreads();
  if (tid == 0){
    #pragma unroll
    for (int k=0;k<9;++k)
      partials[(size_t)blockIdx.x*9 + k] = sm[0][k]+sm[1][k]+sm[2][k]+sm[3][k];
  }
}

// ---------------------------------------------------------------- finalize
// Deterministic double-precision reduction of NTOT block partials.
__global__ __launch_bounds__(256) void yolo_final(const float* __restrict__ partials,
                                                  float* __restrict__ out){
  double acc[9] = {0,0,0,0,0,0,0,0,0};
  for (int b = threadIdx.x; b < NTOT; b += 256){
    #pragma unroll
    for (int k=0;k<9;++k) acc[k] += (double)partials[(size_t)b*9 + k];
  }
  __shared__ double sm[4][9];
  #pragma unroll
  for (int k=0;k<9;++k){
    double v = acc[k];
    for (int off=32; off>0; off>>=1) v += __shfl_down(v, off, 64);
    acc[k] = v;
  }
  int lane = threadIdx.x & 63, wid = threadIdx.x >> 6;
  if (lane == 0){
    #pragma unroll
    for (int k=0;k<9;++k) sm[wid][k] = acc[k];
  }
  __syncthreads();
  if (threadIdx.x == 0){
    double S[9];
    #pragma unroll
    for (int k=0;k<9;++k) S[k] = sm[0][k]+sm[1][k]+sm[2][k]+sm[3][k];
    const double Nf = (double)NCELL;
    double n_m  = S[0];
    double n_nm = (double)NCELL + S[1];   // S[1] is the (negative) deficit
    double lx = S[2]/Nf/n_m;
    double ly = S[3]/Nf/n_m;
    double lw = S[4]/Nf/n_m;
    double lh = S[5]/Nf/n_m;
    double lconf = S[6]/Nf/n_m + 0.5*S[7]/Nf/n_nm;
    double lcls  = S[8]/(n_m*(double)Cn)/n_m;
    double loss  = 2.5*(lx+ly) + 2.5*(lw+lh) + lconf + lcls;
    out[0]=(float)loss; out[1]=(float)lx; out[2]=(float)ly;
    out[3]=(float)lw;   out[4]=(float)lh; out[5]=(float)lconf; out[6]=(float)lcls;
  }
}

extern "C" void kernel_launch(void* const* d_in, const int* in_sizes, int n_in,
                              void* d_out, int out_size, void* d_ws, size_t ws_size,
                              hipStream_t stream) {
  const float* in  = (const float*)d_in[0];   // (B, 255, 76, 76) fp32
  const float* tgt = (const float*)d_in[1];   // (B, 50, 5) fp32
  float* out = (float*)d_out;                 // 7 scalars

  float* partials = (float*)d_ws;             // NTOT*9 floats ≈ 14 KB

  yolo_main <<<NTOT, NTHREADS, 0, stream>>>(in, tgt, partials);
  yolo_final<<<1, 256, 0, stream>>>(partials, out);
}